// Round 1
// baseline (157.837 us; speedup 1.0000x reference)
//
#include <hip/hip_runtime.h>
#include <math.h>

namespace {

constexpr int K = 256, D = 256, P = 40, C = 32;
constexpr int KP = K * P;

__device__ __forceinline__ float tanh_fast(float x) {
  // tanh(x) = 1 - 2/(exp(2x)+1); safe at +-inf ends
  float e = __expf(2.0f * x);
  return 1.0f - __fdividef(2.0f, e + 1.0f);
}

// ---------------- norms: inv[k,p] = 1/max(||x[k,:,p]||, 1e-12) ----------------
__global__ __launch_bounds__(256) void knorm(const float* __restrict__ x,
                                             float* __restrict__ inv) {
  int idx = blockIdx.x * 256 + threadIdx.x;
  if (idx >= KP) return;
  int k = idx / P, p = idx - k * P;
  const float* base = x + (size_t)k * D * P + p;
  float ss = 0.f;
#pragma unroll 4
  for (int d = 0; d < D; ++d) {
    float v = base[(size_t)d * P];
    ss = fmaf(v, v, ss);
  }
  float n = fmaxf(sqrtf(ss), 1e-12f);
  inv[idx] = 1.0f / n;
}

// ------------- transpose+normalize: xt[p][a][d] = x[a,d,p] * inv[a,p] -------------
// block: (a, d-tile of 64). Source chunk x[a, d0..d0+63, :] is CONTIGUOUS (2560 floats).
__global__ __launch_bounds__(256) void ktrans(const float* __restrict__ x,
                                              const float* __restrict__ inv,
                                              float* __restrict__ xt) {
  __shared__ __align__(16) float tile[64 * P];  // 10 KiB
  const int a = blockIdx.x;
  const int d0 = blockIdx.y * 64;
  const float4* src4 = (const float4*)(x + ((size_t)a * D + d0) * P);
  float4* t4 = (float4*)tile;
#pragma unroll
  for (int i = threadIdx.x; i < (64 * P) / 4; i += 256) t4[i] = src4[i];
  __syncthreads();
  for (int i = threadIdx.x; i < 64 * P; i += 256) {
    int p = i >> 6, dd = i & 63;
    xt[((size_t)p * K + a) * D + d0 + dd] = tile[dd * P + p] * inv[a * P + p];
  }
}

// ------------- per-p SGEMM: S[p][a][b] = dot(En[p][a][:], Tn[p][b][:]) -------------
__global__ __launch_bounds__(256) void kgemm(const float* __restrict__ En,
                                             const float* __restrict__ Tn,
                                             float* __restrict__ S) {
  constexpr int BM = 128, BN = 64, DC = 8;
  __shared__ __align__(16) float As[DC][BM];
  __shared__ __align__(16) float Bs[DC][BN];
  const int p = blockIdx.z;
  const int a0 = blockIdx.y * BM;
  const int b0 = blockIdx.x * BN;
  const float* A = En + (size_t)p * K * D;
  const float* B = Tn + (size_t)p * K * D;
  const int t = threadIdx.x;
  const int tx = t & 15, ty = t >> 4;           // micro-tile: 8a x 4b
  const int aa = t >> 1, adq = (t & 1) * 4;     // A staging: 128a x 8d
  const int bb = (t & 127) >> 1, bdq = (t & 1) * 4;  // B staging (t<128): 64b x 8d

  float acc[8][4];
#pragma unroll
  for (int i = 0; i < 8; ++i)
#pragma unroll
    for (int j = 0; j < 4; ++j) acc[i][j] = 0.f;

  for (int d0 = 0; d0 < D; d0 += DC) {
    float4 av = *(const float4*)(A + (size_t)(a0 + aa) * D + d0 + adq);
    float4 bv;
    if (t < 128) bv = *(const float4*)(B + (size_t)(b0 + bb) * D + d0 + bdq);
    As[adq + 0][aa] = av.x;
    As[adq + 1][aa] = av.y;
    As[adq + 2][aa] = av.z;
    As[adq + 3][aa] = av.w;
    if (t < 128) {
      Bs[bdq + 0][bb] = bv.x;
      Bs[bdq + 1][bb] = bv.y;
      Bs[bdq + 2][bb] = bv.z;
      Bs[bdq + 3][bb] = bv.w;
    }
    __syncthreads();
#pragma unroll
    for (int dd = 0; dd < DC; ++dd) {
      float4 a0v = *(const float4*)&As[dd][ty * 8];
      float4 a1v = *(const float4*)&As[dd][ty * 8 + 4];
      float4 bfv = *(const float4*)&Bs[dd][tx * 4];
      float af[8] = {a0v.x, a0v.y, a0v.z, a0v.w, a1v.x, a1v.y, a1v.z, a1v.w};
      float bf[4] = {bfv.x, bfv.y, bfv.z, bfv.w};
#pragma unroll
      for (int i = 0; i < 8; ++i)
#pragma unroll
        for (int j = 0; j < 4; ++j) acc[i][j] = fmaf(af[i], bf[j], acc[i][j]);
    }
    __syncthreads();
  }
  float* Sp = S + (size_t)p * K * K;
#pragma unroll
  for (int i = 0; i < 8; ++i) {
    float4 v = make_float4(acc[i][0], acc[i][1], acc[i][2], acc[i][3]);
    *(float4*)(Sp + (size_t)(a0 + ty * 8 + i) * K + b0 + tx * 4) = v;
  }
}

// ------------- epilogue: MLP over 40 p-slices, weighted average -------------
__global__ __launch_bounds__(256) void kepi(const float* __restrict__ S,
                                            const float* __restrict__ pho_w,
                                            const float* __restrict__ fc1w,
                                            const float* __restrict__ fc1b,
                                            const float* __restrict__ fc2w,
                                            float* __restrict__ out) {
  __shared__ float w1[C], b1[C], w2[C], pw[P];
  const int t = threadIdx.x;
  if (t < C) {
    w1[t] = fc1w[t];
    b1[t] = fc1b[t];
    w2[t] = fc2w[t];
  }
  if (t < P) {
    float wmin = pho_w[0], wmax = pho_w[0];
    for (int i = 1; i < P; ++i) {
      float v = pho_w[i];
      wmin = fminf(wmin, v);
      wmax = fmaxf(wmax, v);
    }
    pw[t] = (pho_w[t] - wmin) / (1e-6f + wmax - wmin);
  }
  __syncthreads();
  const int idx = blockIdx.x * 256 + t;
  float score = 0.f, nz = 0.f;
  for (int p = 0; p < P; ++p) {
    float s = S[(size_t)p * K * K + idx];
    float g = 0.f;
#pragma unroll
    for (int c = 0; c < C; ++c) g = fmaf(tanh_fast(fmaf(s, w1[c], b1[c])), w2[c], g);
    float f = tanh_fast(g * s);
    score = fmaf(f, pw[p], score);
    if (s != 0.0f) nz += pw[p];
  }
  out[idx] = score / (nz + 1e-6f);
}

// ------------- emergency fallback (no workspace needed) -------------
__global__ __launch_bounds__(256) void kmono(const float* __restrict__ enroll,
                                             const float* __restrict__ test,
                                             const float* __restrict__ pho_w,
                                             const float* __restrict__ fc1w,
                                             const float* __restrict__ fc1b,
                                             const float* __restrict__ fc2w,
                                             float* __restrict__ out) {
  __shared__ float w1[C], b1[C], w2[C], pw[P];
  const int t = threadIdx.x;
  if (t < C) {
    w1[t] = fc1w[t];
    b1[t] = fc1b[t];
    w2[t] = fc2w[t];
  }
  if (t < P) {
    float wmin = pho_w[0], wmax = pho_w[0];
    for (int i = 1; i < P; ++i) {
      float v = pho_w[i];
      wmin = fminf(wmin, v);
      wmax = fmaxf(wmax, v);
    }
    pw[t] = (pho_w[t] - wmin) / (1e-6f + wmax - wmin);
  }
  __syncthreads();
  const int idx = blockIdx.x * 256 + t;
  const int a = idx >> 8, b = idx & 255;
  float score = 0.f, nz = 0.f;
  for (int p = 0; p < P; ++p) {
    float se = 0.f, st = 0.f, dot = 0.f;
    for (int d = 0; d < D; ++d) {
      float ev = enroll[((size_t)a * D + d) * P + p];
      float tv = test[((size_t)b * D + d) * P + p];
      se = fmaf(ev, ev, se);
      st = fmaf(tv, tv, st);
      dot = fmaf(ev, tv, dot);
    }
    float s = dot * (1.0f / fmaxf(sqrtf(se), 1e-12f)) * (1.0f / fmaxf(sqrtf(st), 1e-12f));
    float g = 0.f;
#pragma unroll
    for (int c = 0; c < C; ++c) g = fmaf(tanh_fast(fmaf(s, w1[c], b1[c])), w2[c], g);
    float f = tanh_fast(g * s);
    score = fmaf(f, pw[p], score);
    if (s != 0.0f) nz += pw[p];
  }
  out[idx] = score / (nz + 1e-6f);
}

}  // namespace

extern "C" void kernel_launch(void* const* d_in, const int* in_sizes, int n_in,
                              void* d_out, int out_size, void* d_ws, size_t ws_size,
                              hipStream_t stream) {
  const float* enroll = (const float*)d_in[0];
  const float* test = (const float*)d_in[1];
  const float* pho_w = (const float*)d_in[2];
  const float* fc1w = (const float*)d_in[3];
  const float* fc1b = (const float*)d_in[4];
  const float* fc2w = (const float*)d_in[5];
  float* out = (float*)d_out;

  const size_t need =
      (size_t)2 * KP * sizeof(float) +              // inv norms
      (size_t)2 * P * K * D * sizeof(float) +       // transposed normalized inputs
      (size_t)P * K * K * sizeof(float);            // same_pho
  if (ws_size >= need) {
    float* inv_e = (float*)d_ws;
    float* inv_t = inv_e + KP;
    float* En = inv_t + KP;
    float* Tn = En + (size_t)P * K * D;
    float* S = Tn + (size_t)P * K * D;
    knorm<<<(KP + 255) / 256, 256, 0, stream>>>(enroll, inv_e);
    knorm<<<(KP + 255) / 256, 256, 0, stream>>>(test, inv_t);
    ktrans<<<dim3(K, D / 64), 256, 0, stream>>>(enroll, inv_e, En);
    ktrans<<<dim3(K, D / 64), 256, 0, stream>>>(test, inv_t, Tn);
    kgemm<<<dim3(K / 64, K / 128, P), 256, 0, stream>>>(En, Tn, S);
    kepi<<<(K * K) / 256, 256, 0, stream>>>(S, pho_w, fc1w, fc1b, fc2w, out);
  } else {
    kmono<<<(K * K) / 256, 256, 0, stream>>>(enroll, test, pho_w, fc1w, fc1b, fc2w, out);
  }
}

// Round 2
// 99.913 us; speedup vs baseline: 1.5797x; 1.5797x over previous
//
#include <hip/hip_runtime.h>
#include <math.h>

namespace {

constexpr int K = 256, D = 256, P = 40, C = 32;
constexpr int KP = K * P;
constexpr int PC = 8, PPB = 5;  // p-chunks for epilogue: 8 chunks x 5 p

__device__ __forceinline__ float tanh_fast(float x) {
  // tanh(x) = 1 - 2/(exp(2x)+1); exact at +-inf ends
  float e = __expf(2.0f * x);
  return 1.0f - __fdividef(2.0f, e + 1.0f);
}

// ---- prep: fused L2-norm + transpose:  xt[p][a][d] = x[a,d,p]/||x[a,:,p]|| ----
// one block per row a; stages the whole 256x40 row (40 KB) in LDS.
__global__ __launch_bounds__(256) void kprep(const float* __restrict__ x,
                                             float* __restrict__ xt) {
  __shared__ __align__(16) float tile[D * P];  // 40 KiB
  __shared__ float inv[P];
  const int a = blockIdx.x;
  const int t = threadIdx.x;
  const float4* src4 = (const float4*)(x + (size_t)a * D * P);
  float4* t4 = (float4*)tile;
#pragma unroll
  for (int i = t; i < (D * P) / 4; i += 256) t4[i] = src4[i];
  __syncthreads();
  if (t < P) {
    float ss = 0.f;
#pragma unroll 8
    for (int d = 0; d < D; ++d) {
      float v = tile[d * P + t];
      ss = fmaf(v, v, ss);
    }
    inv[t] = 1.0f / fmaxf(sqrtf(ss), 1e-12f);
  }
  __syncthreads();
  // i = p*256 + d ; wave writes 64 consecutive d of one p -> coalesced 256B
  for (int i = t; i < D * P; i += 256) {
    int p = i >> 8, d = i & 255;
    xt[((size_t)p * K + a) * D + d] = tile[d * P + p] * inv[p];
  }
}

// ---- per-p SGEMM: S[p][a][b] = dot(En[p][a][:], Tn[p][b][:]) ----
// BM=BN=64, DC=16, 256 threads, 4x4 micro-tile. grid (4,4,40)=640 blocks.
__global__ __launch_bounds__(256) void kgemm(const float* __restrict__ En,
                                             const float* __restrict__ Tn,
                                             float* __restrict__ S) {
  constexpr int BM = 64, BN = 64, DC = 16;
  __shared__ __align__(16) float As[DC][BM];  // 4 KiB
  __shared__ __align__(16) float Bs[DC][BN];  // 4 KiB
  const int p = blockIdx.z;
  const int a0 = blockIdx.y * BM;
  const int b0 = blockIdx.x * BN;
  const float* A = En + (size_t)p * K * D;
  const float* B = Tn + (size_t)p * K * D;
  const int t = threadIdx.x;
  const int tx = t & 15, ty = t >> 4;        // micro-tile coords (b, a)
  const int row = t >> 2, dq = (t & 3) * 4;  // staging: 64 rows x 16 d

  float acc[4][4];
#pragma unroll
  for (int i = 0; i < 4; ++i)
#pragma unroll
    for (int j = 0; j < 4; ++j) acc[i][j] = 0.f;

  for (int d0 = 0; d0 < D; d0 += DC) {
    float4 av = *(const float4*)(A + (size_t)(a0 + row) * D + d0 + dq);
    float4 bv = *(const float4*)(B + (size_t)(b0 + row) * D + d0 + dq);
    As[dq + 0][row] = av.x;
    As[dq + 1][row] = av.y;
    As[dq + 2][row] = av.z;
    As[dq + 3][row] = av.w;
    Bs[dq + 0][row] = bv.x;
    Bs[dq + 1][row] = bv.y;
    Bs[dq + 2][row] = bv.z;
    Bs[dq + 3][row] = bv.w;
    __syncthreads();
#pragma unroll
    for (int dd = 0; dd < DC; ++dd) {
      float4 afv = *(const float4*)&As[dd][ty * 4];
      float4 bfv = *(const float4*)&Bs[dd][tx * 4];
      float af[4] = {afv.x, afv.y, afv.z, afv.w};
      float bf[4] = {bfv.x, bfv.y, bfv.z, bfv.w};
#pragma unroll
      for (int i = 0; i < 4; ++i)
#pragma unroll
        for (int j = 0; j < 4; ++j) acc[i][j] = fmaf(af[i], bf[j], acc[i][j]);
    }
    __syncthreads();
  }
  float* Sp = S + (size_t)p * K * K;
#pragma unroll
  for (int i = 0; i < 4; ++i) {
    float4 v = make_float4(acc[i][0], acc[i][1], acc[i][2], acc[i][3]);
    *(float4*)(Sp + (size_t)(a0 + ty * 4 + i) * K + b0 + tx * 4) = v;
  }
}

// ---- epilogue partials: each block does 5 of the 40 p's for 256 outputs ----
__global__ __launch_bounds__(256) void kepi_part(const float* __restrict__ S,
                                                 const float* __restrict__ pho_w,
                                                 const float* __restrict__ fc1w,
                                                 const float* __restrict__ fc1b,
                                                 const float* __restrict__ fc2w,
                                                 float* __restrict__ part) {
  __shared__ float w1[C], b1[C], w2[C], pw[P];
  const int t = threadIdx.x;
  if (t < C) {
    w1[t] = fc1w[t];
    b1[t] = fc1b[t];
    w2[t] = fc2w[t];
  }
  if (t < P) {
    float wmin = pho_w[0], wmax = pho_w[0];
    for (int i = 1; i < P; ++i) {
      float v = pho_w[i];
      wmin = fminf(wmin, v);
      wmax = fmaxf(wmax, v);
    }
    pw[t] = (pho_w[t] - wmin) / (1e-6f + wmax - wmin);
  }
  __syncthreads();
  const int idx = blockIdx.x * 256 + t;
  const int pc = blockIdx.y;
  float score = 0.f, nz = 0.f;
#pragma unroll
  for (int pp = 0; pp < PPB; ++pp) {
    const int p = pc * PPB + pp;
    float s = S[(size_t)p * K * K + idx];
    float g = 0.f;
#pragma unroll
    for (int c = 0; c < C; ++c) g = fmaf(tanh_fast(fmaf(s, w1[c], b1[c])), w2[c], g);
    float f = tanh_fast(g * s);
    score = fmaf(f, pw[p], score);
    if (s != 0.0f) nz += pw[p];
  }
  part[((size_t)pc * 2 + 0) * (K * K) + idx] = score;
  part[((size_t)pc * 2 + 1) * (K * K) + idx] = nz;
}

// ---- finalize: reduce the 8 p-chunk partials ----
__global__ __launch_bounds__(256) void kfin(const float* __restrict__ part,
                                            float* __restrict__ out) {
  const int idx = blockIdx.x * 256 + threadIdx.x;
  float score = 0.f, nz = 0.f;
#pragma unroll
  for (int pc = 0; pc < PC; ++pc) {
    score += part[((size_t)pc * 2 + 0) * (K * K) + idx];
    nz += part[((size_t)pc * 2 + 1) * (K * K) + idx];
  }
  out[idx] = score / (nz + 1e-6f);
}

// ---- emergency fallback (no workspace needed) ----
__global__ __launch_bounds__(256) void kmono(const float* __restrict__ enroll,
                                             const float* __restrict__ test,
                                             const float* __restrict__ pho_w,
                                             const float* __restrict__ fc1w,
                                             const float* __restrict__ fc1b,
                                             const float* __restrict__ fc2w,
                                             float* __restrict__ out) {
  __shared__ float w1[C], b1[C], w2[C], pw[P];
  const int t = threadIdx.x;
  if (t < C) {
    w1[t] = fc1w[t];
    b1[t] = fc1b[t];
    w2[t] = fc2w[t];
  }
  if (t < P) {
    float wmin = pho_w[0], wmax = pho_w[0];
    for (int i = 1; i < P; ++i) {
      float v = pho_w[i];
      wmin = fminf(wmin, v);
      wmax = fmaxf(wmax, v);
    }
    pw[t] = (pho_w[t] - wmin) / (1e-6f + wmax - wmin);
  }
  __syncthreads();
  const int idx = blockIdx.x * 256 + t;
  const int a = idx >> 8, b = idx & 255;
  float score = 0.f, nz = 0.f;
  for (int p = 0; p < P; ++p) {
    float se = 0.f, st = 0.f, dot = 0.f;
    for (int d = 0; d < D; ++d) {
      float ev = enroll[((size_t)a * D + d) * P + p];
      float tv = test[((size_t)b * D + d) * P + p];
      se = fmaf(ev, ev, se);
      st = fmaf(tv, tv, st);
      dot = fmaf(ev, tv, dot);
    }
    float s = dot * (1.0f / fmaxf(sqrtf(se), 1e-12f)) * (1.0f / fmaxf(sqrtf(st), 1e-12f));
    float g = 0.f;
#pragma unroll
    for (int c = 0; c < C; ++c) g = fmaf(tanh_fast(fmaf(s, w1[c], b1[c])), w2[c], g);
    float f = tanh_fast(g * s);
    score = fmaf(f, pw[p], score);
    if (s != 0.0f) nz += pw[p];
  }
  out[idx] = score / (nz + 1e-6f);
}

}  // namespace

extern "C" void kernel_launch(void* const* d_in, const int* in_sizes, int n_in,
                              void* d_out, int out_size, void* d_ws, size_t ws_size,
                              hipStream_t stream) {
  const float* enroll = (const float*)d_in[0];
  const float* test = (const float*)d_in[1];
  const float* pho_w = (const float*)d_in[2];
  const float* fc1w = (const float*)d_in[3];
  const float* fc1b = (const float*)d_in[4];
  const float* fc2w = (const float*)d_in[5];
  float* out = (float*)d_out;

  const size_t need = (size_t)2 * P * K * D * sizeof(float) +  // En, Tn
                      (size_t)P * K * K * sizeof(float);       // S
  if (ws_size >= need) {
    float* En = (float*)d_ws;
    float* Tn = En + (size_t)P * K * D;
    float* S = Tn + (size_t)P * K * D;
    float* part = En;  // En is dead once kgemm finishes; 8*2*64K floats < En size
    kprep<<<K, 256, 0, stream>>>(enroll, En);
    kprep<<<K, 256, 0, stream>>>(test, Tn);
    kgemm<<<dim3(K / 64, K / 64, P), 256, 0, stream>>>(En, Tn, S);
    kepi_part<<<dim3((K * K) / 256, PC), 256, 0, stream>>>(S, pho_w, fc1w, fc1b, fc2w, part);
    kfin<<<(K * K) / 256, 256, 0, stream>>>(part, out);
  } else {
    kmono<<<(K * K) / 256, 256, 0, stream>>>(enroll, test, pho_w, fc1w, fc1b, fc2w, out);
  }
}

// Round 3
// 64.120 us; speedup vs baseline: 2.4616x; 1.5582x over previous
//
#include <hip/hip_runtime.h>
#include <math.h>

namespace {

constexpr int K = 256, D = 256, P = 40, C = 32;
constexpr int PC = 8, PPB = 5;   // p-chunks for epilogue: 8 chunks x 5 p
constexpr int LN = 4096;         // LUT intervals over s in [-1,1]

__device__ __forceinline__ float tanh_fast(float x) {
  // tanh(x) = 1 - 2/(exp(2x)+1); exact at +-inf ends
  float e = __expf(2.0f * x);
  return 1.0f - __fdividef(2.0f, e + 1.0f);
}

// ---- LUT build: tab[i] = F(-1 + i*2/LN), F(s) = tanh(s * sum_c w2[c]*tanh(s*w1[c]+b1[c])) ----
__global__ __launch_bounds__(256) void ktab(const float* __restrict__ fc1w,
                                            const float* __restrict__ fc1b,
                                            const float* __restrict__ fc2w,
                                            float* __restrict__ tab) {
  int i = blockIdx.x * 256 + threadIdx.x;
  if (i > LN) return;
  float s = -1.0f + (float)i * (2.0f / LN);
  float g = 0.f;
#pragma unroll
  for (int c = 0; c < C; ++c) g = fmaf(tanh_fast(fmaf(s, fc1w[c], fc1b[c])), fc2w[c], g);
  tab[i] = tanh_fast(g * s);
}

// ---- prep: fused L2-norm + transpose:  xt[p][a][d] = x[a,d,p]/||x[a,:,p]|| ----
__global__ __launch_bounds__(256) void kprep(const float* __restrict__ x,
                                             float* __restrict__ xt) {
  __shared__ __align__(16) float tile[D * P];  // 40 KiB
  __shared__ float inv[P];
  const int a = blockIdx.x;
  const int t = threadIdx.x;
  const float4* src4 = (const float4*)(x + (size_t)a * D * P);
  float4* t4 = (float4*)tile;
#pragma unroll
  for (int i = t; i < (D * P) / 4; i += 256) t4[i] = src4[i];
  __syncthreads();
  if (t < P) {
    float ss = 0.f;
#pragma unroll 8
    for (int d = 0; d < D; ++d) {
      float v = tile[d * P + t];
      ss = fmaf(v, v, ss);
    }
    inv[t] = 1.0f / fmaxf(sqrtf(ss), 1e-12f);
  }
  __syncthreads();
  for (int i = t; i < D * P; i += 256) {
    int p = i >> 8, d = i & 255;
    xt[((size_t)p * K + a) * D + d] = tile[d * P + p] * inv[p];
  }
}

// ---- per-p SGEMM, double-buffered: S[p][a][b] = dot(En[p][a][:], Tn[p][b][:]) ----
__global__ __launch_bounds__(256) void kgemm(const float* __restrict__ En,
                                             const float* __restrict__ Tn,
                                             float* __restrict__ S) {
  constexpr int BM = 64, BN = 64, DC = 16, NT = D / DC;
  __shared__ __align__(16) float As[2][DC][BM];  // 8 KiB
  __shared__ __align__(16) float Bs[2][DC][BN];  // 8 KiB
  const int p = blockIdx.z;
  const int a0 = blockIdx.y * BM;
  const int b0 = blockIdx.x * BN;
  const int t = threadIdx.x;
  const int tx = t & 15, ty = t >> 4;        // micro-tile coords (b, a)
  const int row = t >> 2, dq = (t & 3) * 4;  // staging: 64 rows x 16 d
  const float* Arow = En + (size_t)p * K * D + (size_t)(a0 + row) * D + dq;
  const float* Brow = Tn + (size_t)p * K * D + (size_t)(b0 + row) * D + dq;

  float4 av = *(const float4*)Arow;
  float4 bv = *(const float4*)Brow;
  As[0][dq + 0][row] = av.x;
  As[0][dq + 1][row] = av.y;
  As[0][dq + 2][row] = av.z;
  As[0][dq + 3][row] = av.w;
  Bs[0][dq + 0][row] = bv.x;
  Bs[0][dq + 1][row] = bv.y;
  Bs[0][dq + 2][row] = bv.z;
  Bs[0][dq + 3][row] = bv.w;
  __syncthreads();

  float acc[4][4];
#pragma unroll
  for (int i = 0; i < 4; ++i)
#pragma unroll
    for (int j = 0; j < 4; ++j) acc[i][j] = 0.f;

  for (int tile = 0; tile < NT; ++tile) {
    const int cur = tile & 1;
    if (tile + 1 < NT) {
      av = *(const float4*)(Arow + (tile + 1) * DC);
      bv = *(const float4*)(Brow + (tile + 1) * DC);
    }
#pragma unroll
    for (int dd = 0; dd < DC; ++dd) {
      float4 afv = *(const float4*)&As[cur][dd][ty * 4];
      float4 bfv = *(const float4*)&Bs[cur][dd][tx * 4];
      float af[4] = {afv.x, afv.y, afv.z, afv.w};
      float bf[4] = {bfv.x, bfv.y, bfv.z, bfv.w};
#pragma unroll
      for (int i = 0; i < 4; ++i)
#pragma unroll
        for (int j = 0; j < 4; ++j) acc[i][j] = fmaf(af[i], bf[j], acc[i][j]);
    }
    if (tile + 1 < NT) {
      const int nxt = cur ^ 1;
      As[nxt][dq + 0][row] = av.x;
      As[nxt][dq + 1][row] = av.y;
      As[nxt][dq + 2][row] = av.z;
      As[nxt][dq + 3][row] = av.w;
      Bs[nxt][dq + 0][row] = bv.x;
      Bs[nxt][dq + 1][row] = bv.y;
      Bs[nxt][dq + 2][row] = bv.z;
      Bs[nxt][dq + 3][row] = bv.w;
    }
    __syncthreads();
  }
  float* Sp = S + (size_t)p * K * K;
#pragma unroll
  for (int i = 0; i < 4; ++i) {
    float4 v = make_float4(acc[i][0], acc[i][1], acc[i][2], acc[i][3]);
    *(float4*)(Sp + (size_t)(a0 + ty * 4 + i) * K + b0 + tx * 4) = v;
  }
}

// ---- epilogue partials via LUT: each block does 5 p's for 256 outputs ----
__global__ __launch_bounds__(256) void kepi_part(const float* __restrict__ S,
                                                 const float* __restrict__ tab,
                                                 const float* __restrict__ pho_w,
                                                 float* __restrict__ part) {
  __shared__ __align__(16) float lt[LN + 4];
  __shared__ float pw[P];
  const int t = threadIdx.x;
  for (int i = t; i <= LN; i += 256) lt[i] = tab[i];
  if (t < P) {
    float wmin = pho_w[0], wmax = pho_w[0];
    for (int i = 1; i < P; ++i) {
      float v = pho_w[i];
      wmin = fminf(wmin, v);
      wmax = fmaxf(wmax, v);
    }
    pw[t] = (pho_w[t] - wmin) / (1e-6f + wmax - wmin);
  }
  __syncthreads();
  const int idx = blockIdx.x * 256 + t;
  const int pc = blockIdx.y;
  float score = 0.f, nz = 0.f;
#pragma unroll
  for (int pp = 0; pp < PPB; ++pp) {
    const int p = pc * PPB + pp;
    float s = S[(size_t)p * (K * K) + idx];
    float u = fmaxf((s + 1.0f) * (LN / 2), 0.0f);
    int i = min((int)u, LN - 1);
    float fr = u - (float)i;
    float F = fmaf(fr, lt[i + 1] - lt[i], lt[i]);
    score = fmaf(F, pw[p], score);
    nz += (s != 0.0f) ? pw[p] : 0.0f;
  }
  part[((size_t)pc * 2 + 0) * (K * K) + idx] = score;
  part[((size_t)pc * 2 + 1) * (K * K) + idx] = nz;
}

// ---- finalize: reduce the 8 p-chunk partials ----
__global__ __launch_bounds__(256) void kfin(const float* __restrict__ part,
                                            float* __restrict__ out) {
  const int idx = blockIdx.x * 256 + threadIdx.x;
  float score = 0.f, nz = 0.f;
#pragma unroll
  for (int pc = 0; pc < PC; ++pc) {
    score += part[((size_t)pc * 2 + 0) * (K * K) + idx];
    nz += part[((size_t)pc * 2 + 1) * (K * K) + idx];
  }
  out[idx] = score / (nz + 1e-6f);
}

// ---- emergency fallback (no workspace needed) ----
__global__ __launch_bounds__(256) void kmono(const float* __restrict__ enroll,
                                             const float* __restrict__ test,
                                             const float* __restrict__ pho_w,
                                             const float* __restrict__ fc1w,
                                             const float* __restrict__ fc1b,
                                             const float* __restrict__ fc2w,
                                             float* __restrict__ out) {
  __shared__ float w1[C], b1[C], w2[C], pw[P];
  const int t = threadIdx.x;
  if (t < C) {
    w1[t] = fc1w[t];
    b1[t] = fc1b[t];
    w2[t] = fc2w[t];
  }
  if (t < P) {
    float wmin = pho_w[0], wmax = pho_w[0];
    for (int i = 1; i < P; ++i) {
      float v = pho_w[i];
      wmin = fminf(wmin, v);
      wmax = fmaxf(wmax, v);
    }
    pw[t] = (pho_w[t] - wmin) / (1e-6f + wmax - wmin);
  }
  __syncthreads();
  const int idx = blockIdx.x * 256 + t;
  const int a = idx >> 8, b = idx & 255;
  float score = 0.f, nz = 0.f;
  for (int p = 0; p < P; ++p) {
    float se = 0.f, st = 0.f, dot = 0.f;
    for (int d = 0; d < D; ++d) {
      float ev = enroll[((size_t)a * D + d) * P + p];
      float tv = test[((size_t)b * D + d) * P + p];
      se = fmaf(ev, ev, se);
      st = fmaf(tv, tv, st);
      dot = fmaf(ev, tv, dot);
    }
    float s = dot * (1.0f / fmaxf(sqrtf(se), 1e-12f)) * (1.0f / fmaxf(sqrtf(st), 1e-12f));
    float g = 0.f;
#pragma unroll
    for (int c = 0; c < C; ++c) g = fmaf(tanh_fast(fmaf(s, w1[c], b1[c])), w2[c], g);
    float f = tanh_fast(g * s);
    score = fmaf(f, pw[p], score);
    if (s != 0.0f) nz += pw[p];
  }
  out[idx] = score / (nz + 1e-6f);
}

}  // namespace

extern "C" void kernel_launch(void* const* d_in, const int* in_sizes, int n_in,
                              void* d_out, int out_size, void* d_ws, size_t ws_size,
                              hipStream_t stream) {
  const float* enroll = (const float*)d_in[0];
  const float* test = (const float*)d_in[1];
  const float* pho_w = (const float*)d_in[2];
  const float* fc1w = (const float*)d_in[3];
  const float* fc1b = (const float*)d_in[4];
  const float* fc2w = (const float*)d_in[5];
  float* out = (float*)d_out;

  const size_t need = (size_t)2 * P * K * D * sizeof(float) +  // En, Tn
                      (size_t)P * K * K * sizeof(float);       // S
  if (ws_size >= need) {
    float* En = (float*)d_ws;
    float* Tn = En + (size_t)P * K * D;
    float* S = Tn + (size_t)P * K * D;
    float* part = En;   // En dead after kgemm; 16*64K floats (4 MB) < En (10.5 MB)
    float* tab = out;   // first LN+1 floats of d_out; dead until kfin overwrites

    ktab<<<(LN + 256) / 256, 256, 0, stream>>>(fc1w, fc1b, fc2w, tab);
    kprep<<<K, 256, 0, stream>>>(enroll, En);
    kprep<<<K, 256, 0, stream>>>(test, Tn);
    kgemm<<<dim3(K / 64, K / 64, P), 256, 0, stream>>>(En, Tn, S);
    kepi_part<<<dim3((K * K) / 256, PC), 256, 0, stream>>>(S, tab, pho_w, part);
    kfin<<<(K * K) / 256, 256, 0, stream>>>(part, out);
  } else {
    kmono<<<(K * K) / 256, 256, 0, stream>>>(enroll, test, pho_w, fc1w, fc1b, fc2w, out);
  }
}

// Round 4
// 51.597 us; speedup vs baseline: 3.0591x; 1.2427x over previous
//
#include <hip/hip_runtime.h>
#include <math.h>

namespace {

constexpr int K = 256, D = 256, P = 40, C = 32;
constexpr int PC = 8, PPB = 5;   // p-chunks for epilogue: 8 chunks x 5 p
constexpr int LN = 4096;         // LUT intervals over s in [-1,1]

typedef __attribute__((ext_vector_type(8))) short bf16x8;
typedef __attribute__((ext_vector_type(4))) float f32x4;

__device__ __forceinline__ float tanh_fast(float x) {
  float e = __expf(2.0f * x);
  return 1.0f - __fdividef(2.0f, e + 1.0f);
}

// round-to-nearest bf16 split: returns (hi16) | (lo16 << 16); hi+lo ~ v to ~2^-18 rel
__device__ __forceinline__ unsigned bf16pair(float v) {
  unsigned u = __float_as_uint(v);
  unsigned hi = (u + 0x7fffu + ((u >> 16) & 1u)) >> 16;
  float lo = v - __uint_as_float(hi << 16);
  unsigned ul = __float_as_uint(lo);
  unsigned lo16 = (ul + 0x7fffu + ((ul >> 16) & 1u)) >> 16;
  return hi | (lo16 << 16);
}

// ---- LUT build: tab[i] = F(-1 + i*2/LN), F(s) = tanh(s * sum_c w2[c]*tanh(s*w1[c]+b1[c])) ----
__global__ __launch_bounds__(256) void ktab(const float* __restrict__ fc1w,
                                            const float* __restrict__ fc1b,
                                            const float* __restrict__ fc2w,
                                            float* __restrict__ tab) {
  int i = blockIdx.x * 256 + threadIdx.x;
  if (i > LN) return;
  float s = -1.0f + (float)i * (2.0f / LN);
  float g = 0.f;
#pragma unroll
  for (int c = 0; c < C; ++c) g = fmaf(tanh_fast(fmaf(s, fc1w[c], fc1b[c])), fc2w[c], g);
  tab[i] = tanh_fast(g * s);
}

// ---- prep: L2-norm + transpose + bf16 hi/lo split ----
// xt (as u32): xt[p][a][d] = pack(hi,lo) of x[a,d,p]/||x[a,:,p]||  -> K-dim 512 bf16
__global__ __launch_bounds__(256) void kprep(const float* __restrict__ x,
                                             unsigned* __restrict__ xt) {
  __shared__ __align__(16) float tile[D * P];  // 40 KiB
  __shared__ float inv[P];
  const int a = blockIdx.x;
  const int t = threadIdx.x;
  const float4* src4 = (const float4*)(x + (size_t)a * D * P);
  float4* t4 = (float4*)tile;
#pragma unroll
  for (int i = t; i < (D * P) / 4; i += 256) t4[i] = src4[i];
  __syncthreads();
  if (t < P) {
    float ss = 0.f;
#pragma unroll 8
    for (int d = 0; d < D; ++d) {
      float v = tile[d * P + t];
      ss = fmaf(v, v, ss);
    }
    inv[t] = 1.0f / fmaxf(sqrtf(ss), 1e-12f);
  }
  __syncthreads();
  for (int i = t; i < D * P; i += 256) {
    int p = i >> 8, d = i & 255;
    float v = tile[d * P + p] * inv[p];
    xt[((size_t)p * K + a) * 256 + d] = bf16pair(v);
  }
}

// ---- per-p MFMA GEMM over split-K=512 bf16: S[p][a][b] = dot(Ep[p][a][:], Tp[p][b][:]) ----
// 64x64 tile, 4 waves = 2x2 quadrants of 32x32, mfma_f32_16x16x32_bf16, BK=64 bf16.
__global__ __launch_bounds__(256) void kgemm(const uint4* __restrict__ Ep,
                                             const uint4* __restrict__ Tp,
                                             float* __restrict__ S) {
  __shared__ uint4 As4[512];  // 8 KiB: 64 rows x 128 B (XOR-swizzled)
  __shared__ uint4 Bs4[512];  // 8 KiB
  const int p = blockIdx.z;
  const int a0 = blockIdx.y * 64, b0 = blockIdx.x * 64;
  const int t = threadIdx.x, lane = t & 63, w = t >> 6;
  const int qr = (w >> 1) * 32, qc = (w & 1) * 32;
  // staging: thread t loads 32 B of row (t>>2), segment (t&3), for A and B
  const int srow = t >> 2, sseg = t & 3;
  const uint4* Ab = Ep + (size_t)p * (K * 64) + (size_t)(a0 + srow) * 64 + sseg * 2;
  const uint4* Bb = Tp + (size_t)p * (K * 64) + (size_t)(b0 + srow) * 64 + sseg * 2;
  const int wsw = (srow & 7) << 4;
  const int wi0 = (srow * 128 + ((sseg * 32) ^ wsw)) >> 4;
  const int wi1 = (srow * 128 + ((sseg * 32 + 16) ^ wsw)) >> 4;
  // fragment read bases: row = q? + rb*16 + (lane&15); swizzle depends only on (lane&7)
  const int l15 = lane & 15, hi16 = (lane >> 4) * 16;
  const int rsw = (l15 & 7) << 4;
  const int rowA0 = (qr + l15) * 128, rowA1 = (qr + 16 + l15) * 128;
  const int rowB0 = (qc + l15) * 128, rowB1 = (qc + 16 + l15) * 128;
  const char* Ac = (const char*)As4;
  const char* Bc = (const char*)Bs4;

  f32x4 acc00 = {0.f, 0.f, 0.f, 0.f}, acc01 = acc00, acc10 = acc00, acc11 = acc00;

  for (int ks = 0; ks < 8; ++ks) {
    uint4 ga0 = Ab[ks * 8], ga1 = Ab[ks * 8 + 1];
    uint4 gb0 = Bb[ks * 8], gb1 = Bb[ks * 8 + 1];
    if (ks) __syncthreads();
    As4[wi0] = ga0;
    As4[wi1] = ga1;
    Bs4[wi0] = gb0;
    Bs4[wi1] = gb1;
    __syncthreads();
#pragma unroll
    for (int kk = 0; kk < 2; ++kk) {
      const int off = (kk * 64 + hi16) ^ rsw;
      bf16x8 af0 = *(const bf16x8*)(Ac + rowA0 + off);
      bf16x8 af1 = *(const bf16x8*)(Ac + rowA1 + off);
      bf16x8 bf0 = *(const bf16x8*)(Bc + rowB0 + off);
      bf16x8 bf1 = *(const bf16x8*)(Bc + rowB1 + off);
      acc00 = __builtin_amdgcn_mfma_f32_16x16x32_bf16(af0, bf0, acc00, 0, 0, 0);
      acc01 = __builtin_amdgcn_mfma_f32_16x16x32_bf16(af0, bf1, acc01, 0, 0, 0);
      acc10 = __builtin_amdgcn_mfma_f32_16x16x32_bf16(af1, bf0, acc10, 0, 0, 0);
      acc11 = __builtin_amdgcn_mfma_f32_16x16x32_bf16(af1, bf1, acc11, 0, 0, 0);
    }
  }
  // C/D: col = lane&15, row = (lane>>4)*4 + j  (within each 16x16 fragment)
  float* Sp = S + (size_t)p * (K * K);
  const int ar = a0 + qr + (lane >> 4) * 4;
  const int bc = b0 + qc + l15;
#pragma unroll
  for (int j = 0; j < 4; ++j) {
    Sp[(size_t)(ar + j) * K + bc] = acc00[j];
    Sp[(size_t)(ar + j) * K + bc + 16] = acc01[j];
    Sp[(size_t)(ar + 16 + j) * K + bc] = acc10[j];
    Sp[(size_t)(ar + 16 + j) * K + bc + 16] = acc11[j];
  }
}

// ---- epilogue partials via LUT: each block does 5 p's for 256 outputs ----
__global__ __launch_bounds__(256) void kepi_part(const float* __restrict__ S,
                                                 const float* __restrict__ tab,
                                                 const float* __restrict__ pho_w,
                                                 float* __restrict__ part) {
  __shared__ __align__(16) float lt[LN + 4];
  __shared__ float pw[P];
  const int t = threadIdx.x;
  for (int i = t; i <= LN; i += 256) lt[i] = tab[i];
  if (t < P) {
    float wmin = pho_w[0], wmax = pho_w[0];
    for (int i = 1; i < P; ++i) {
      float v = pho_w[i];
      wmin = fminf(wmin, v);
      wmax = fmaxf(wmax, v);
    }
    pw[t] = (pho_w[t] - wmin) / (1e-6f + wmax - wmin);
  }
  __syncthreads();
  const int idx = blockIdx.x * 256 + t;
  const int pc = blockIdx.y;
  float score = 0.f, nz = 0.f;
#pragma unroll
  for (int pp = 0; pp < PPB; ++pp) {
    const int p = pc * PPB + pp;
    float s = S[(size_t)p * (K * K) + idx];
    float u = fmaxf((s + 1.0f) * (LN / 2), 0.0f);
    int i = min((int)u, LN - 1);
    float fr = u - (float)i;
    float F = fmaf(fr, lt[i + 1] - lt[i], lt[i]);
    score = fmaf(F, pw[p], score);
    nz += (s != 0.0f) ? pw[p] : 0.0f;
  }
  part[((size_t)pc * 2 + 0) * (K * K) + idx] = score;
  part[((size_t)pc * 2 + 1) * (K * K) + idx] = nz;
}

// ---- finalize: reduce the 8 p-chunk partials ----
__global__ __launch_bounds__(256) void kfin(const float* __restrict__ part,
                                            float* __restrict__ out) {
  const int idx = blockIdx.x * 256 + threadIdx.x;
  float score = 0.f, nz = 0.f;
#pragma unroll
  for (int pc = 0; pc < PC; ++pc) {
    score += part[((size_t)pc * 2 + 0) * (K * K) + idx];
    nz += part[((size_t)pc * 2 + 1) * (K * K) + idx];
  }
  out[idx] = score / (nz + 1e-6f);
}

// ---- emergency fallback (no workspace needed) ----
__global__ __launch_bounds__(256) void kmono(const float* __restrict__ enroll,
                                             const float* __restrict__ test,
                                             const float* __restrict__ pho_w,
                                             const float* __restrict__ fc1w,
                                             const float* __restrict__ fc1b,
                                             const float* __restrict__ fc2w,
                                             float* __restrict__ out) {
  __shared__ float w1[C], b1[C], w2[C], pw[P];
  const int t = threadIdx.x;
  if (t < C) {
    w1[t] = fc1w[t];
    b1[t] = fc1b[t];
    w2[t] = fc2w[t];
  }
  if (t < P) {
    float wmin = pho_w[0], wmax = pho_w[0];
    for (int i = 1; i < P; ++i) {
      float v = pho_w[i];
      wmin = fminf(wmin, v);
      wmax = fmaxf(wmax, v);
    }
    pw[t] = (pho_w[t] - wmin) / (1e-6f + wmax - wmin);
  }
  __syncthreads();
  const int idx = blockIdx.x * 256 + t;
  const int a = idx >> 8, b = idx & 255;
  float score = 0.f, nz = 0.f;
  for (int p = 0; p < P; ++p) {
    float se = 0.f, st = 0.f, dot = 0.f;
    for (int d = 0; d < D; ++d) {
      float ev = enroll[((size_t)a * D + d) * P + p];
      float tv = test[((size_t)b * D + d) * P + p];
      se = fmaf(ev, ev, se);
      st = fmaf(tv, tv, st);
      dot = fmaf(ev, tv, dot);
    }
    float s = dot * (1.0f / fmaxf(sqrtf(se), 1e-12f)) * (1.0f / fmaxf(sqrtf(st), 1e-12f));
    float g = 0.f;
#pragma unroll
    for (int c = 0; c < C; ++c) g = fmaf(tanh_fast(fmaf(s, w1[c], b1[c])), w2[c], g);
    float f = tanh_fast(g * s);
    score = fmaf(f, pw[p], score);
    if (s != 0.0f) nz += pw[p];
  }
  out[idx] = score / (nz + 1e-6f);
}

}  // namespace

extern "C" void kernel_launch(void* const* d_in, const int* in_sizes, int n_in,
                              void* d_out, int out_size, void* d_ws, size_t ws_size,
                              hipStream_t stream) {
  const float* enroll = (const float*)d_in[0];
  const float* test = (const float*)d_in[1];
  const float* pho_w = (const float*)d_in[2];
  const float* fc1w = (const float*)d_in[3];
  const float* fc1b = (const float*)d_in[4];
  const float* fc2w = (const float*)d_in[5];
  float* out = (float*)d_out;

  const size_t sz_pair = (size_t)P * K * 512 * sizeof(short);  // 10.5 MB each
  const size_t need = 2 * sz_pair + (size_t)P * K * K * sizeof(float);
  if (ws_size >= need) {
    unsigned* Ep = (unsigned*)d_ws;
    unsigned* Tp = Ep + sz_pair / 4;
    float* S = (float*)(Tp + sz_pair / 4);
    float* part = (float*)Ep;  // Ep dead after kgemm; 16*64K floats (4 MB) < 10.5 MB
    float* tab = out;          // first LN+1 floats of d_out; dead until kfin overwrites

    ktab<<<(LN + 256) / 256, 256, 0, stream>>>(fc1w, fc1b, fc2w, tab);
    kprep<<<K, 256, 0, stream>>>(enroll, Ep);
    kprep<<<K, 256, 0, stream>>>(test, Tp);
    kgemm<<<dim3(K / 64, K / 64, P), 256, 0, stream>>>((const uint4*)Ep, (const uint4*)Tp, S);
    kepi_part<<<dim3((K * K) / 256, PC), 256, 0, stream>>>(S, tab, pho_w, part);
    kfin<<<(K * K) / 256, 256, 0, stream>>>(part, out);
  } else {
    kmono<<<(K * K) / 256, 256, 0, stream>>>(enroll, test, pho_w, fc1w, fc1b, fc2w, out);
  }
}

// Round 5
// 50.952 us; speedup vs baseline: 3.0978x; 1.0127x over previous
//
#include <hip/hip_runtime.h>
#include <math.h>

namespace {

constexpr int K = 256, D = 256, P = 40, C = 32;
constexpr int LN = 4096;          // LUT intervals over s in [-1,1]
constexpr int NOUT = K * K;       // 65536

typedef __attribute__((ext_vector_type(8))) short bf16x8;
typedef __attribute__((ext_vector_type(4))) float f32x4;

__device__ __forceinline__ float tanh_fast(float x) {
  float e = __expf(2.0f * x);
  return 1.0f - __fdividef(2.0f, e + 1.0f);
}

// round-to-nearest bf16 split: returns (hi16) | (lo16 << 16); hi+lo ~ v to ~2^-18 rel
__device__ __forceinline__ unsigned bf16pair(float v) {
  unsigned u = __float_as_uint(v);
  unsigned hi = (u + 0x7fffu + ((u >> 16) & 1u)) >> 16;
  float lo = v - __uint_as_float(hi << 16);
  unsigned ul = __float_as_uint(lo);
  unsigned lo16 = (ul + 0x7fffu + ((ul >> 16) & 1u)) >> 16;
  return hi | (lo16 << 16);
}

// ---- init: zero acc planes + build LUT + normalized pho weights, one launch ----
__global__ __launch_bounds__(256) void kinit(const float* __restrict__ fc1w,
                                             const float* __restrict__ fc1b,
                                             const float* __restrict__ fc2w,
                                             const float* __restrict__ pho_w,
                                             float* __restrict__ acc,
                                             float* __restrict__ tab,
                                             float* __restrict__ pw) {
  int gi = blockIdx.x * 256 + threadIdx.x;
  if (gi < 2 * NOUT) {
    acc[gi] = 0.f;
    return;
  }
  gi -= 2 * NOUT;
  if (gi <= LN) {
    float s = -1.0f + (float)gi * (2.0f / LN);
    float g = 0.f;
#pragma unroll
    for (int c = 0; c < C; ++c) g = fmaf(tanh_fast(fmaf(s, fc1w[c], fc1b[c])), fc2w[c], g);
    tab[gi] = tanh_fast(g * s);
    return;
  }
  gi -= LN + 1;
  if (gi < P) {
    float wmin = pho_w[0], wmax = pho_w[0];
    for (int i = 1; i < P; ++i) {
      float v = pho_w[i];
      wmin = fminf(wmin, v);
      wmax = fmaxf(wmax, v);
    }
    pw[gi] = (pho_w[gi] - wmin) / (1e-6f + wmax - wmin);
  }
}

// ---- prep: L2-norm + transpose + bf16 hi/lo split; grid 2K (enroll then test) ----
__global__ __launch_bounds__(256) void kprep(const float* __restrict__ e,
                                             const float* __restrict__ ts,
                                             unsigned* __restrict__ Ep,
                                             unsigned* __restrict__ Tp) {
  __shared__ float tile[D * 41];  // padded stride 41: bank-conflict-free
  __shared__ float inv[P];
  const int bid = blockIdx.x;
  const float* x = (bid < K) ? e : ts;
  unsigned* xt = (bid < K) ? Ep : Tp;
  const int a = bid & (K - 1);
  const int t = threadIdx.x;
  const float4* src4 = (const float4*)(x + (size_t)a * D * P);
#pragma unroll
  for (int i4 = t; i4 < (D * P) / 4; i4 += 256) {
    float4 v = src4[i4];  // row length 40 = 10 float4 -> each float4 within one d
    int d = i4 / 10;
    int p0 = (i4 - d * 10) * 4;
    float* dst = &tile[d * 41 + p0];
    dst[0] = v.x;
    dst[1] = v.y;
    dst[2] = v.z;
    dst[3] = v.w;
  }
  __syncthreads();
  if (t < P) {
    float ss = 0.f;
#pragma unroll 8
    for (int d = 0; d < D; ++d) {
      float v = tile[d * 41 + t];
      ss = fmaf(v, v, ss);
    }
    inv[t] = 1.0f / fmaxf(sqrtf(ss), 1e-12f);
  }
  __syncthreads();
  for (int i = t; i < D * P; i += 256) {
    int p = i >> 8, d = i & 255;
    xt[((size_t)p * K + a) * 256 + d] = bf16pair(tile[d * 41 + p] * inv[p]);
  }
}

// ---- per-p MFMA GEMM (split-K=512 bf16) with fused LUT epilogue + atomic accumulate ----
// 64x64 tile, 4 waves = 2x2 quadrants of 32x32, mfma_f32_16x16x32_bf16, double-buffered.
__global__ __launch_bounds__(256) void kgemm(const uint4* __restrict__ Ep,
                                             const uint4* __restrict__ Tp,
                                             const float* __restrict__ tab,
                                             const float* __restrict__ pw,
                                             float* __restrict__ accS,
                                             float* __restrict__ accN) {
  __shared__ uint4 As4[2][512];  // 2 x 8 KiB: 64 rows x 128 B (XOR-swizzled)
  __shared__ uint4 Bs4[2][512];
  __shared__ __align__(16) float lt[LN + 1];  // 16.4 KiB
  const int p = blockIdx.z;
  const int a0 = blockIdx.y * 64, b0 = blockIdx.x * 64;
  const int t = threadIdx.x, lane = t & 63, w = t >> 6;
  const int qr = (w >> 1) * 32, qc = (w & 1) * 32;
  const int srow = t >> 2, sseg = t & 3;
  const uint4* Ab = Ep + (size_t)p * (K * 64) + (size_t)(a0 + srow) * 64 + sseg * 2;
  const uint4* Bb = Tp + (size_t)p * (K * 64) + (size_t)(b0 + srow) * 64 + sseg * 2;
  const int wsw = (srow & 7) << 4;
  const int wi0 = (srow * 128 + ((sseg * 32) ^ wsw)) >> 4;
  const int wi1 = (srow * 128 + ((sseg * 32 + 16) ^ wsw)) >> 4;
  const int l15 = lane & 15, hi16 = (lane >> 4) * 16;
  const int rsw = (l15 & 7) << 4;
  const int rowA0 = (qr + l15) * 128, rowA1 = (qr + 16 + l15) * 128;
  const int rowB0 = (qc + l15) * 128, rowB1 = (qc + 16 + l15) * 128;

  // stage LUT (in flight under the K-loop; visibility via K-loop barriers)
  for (int i = t; i <= LN; i += 256) lt[i] = tab[i];

  f32x4 acc00 = {0.f, 0.f, 0.f, 0.f}, acc01 = acc00, acc10 = acc00, acc11 = acc00;
  uint4 ga0 = Ab[0], ga1 = Ab[1];
  uint4 gb0 = Bb[0], gb1 = Bb[1];

  for (int ks = 0; ks < 8; ++ks) {
    const int cur = ks & 1;
    As4[cur][wi0] = ga0;
    As4[cur][wi1] = ga1;
    Bs4[cur][wi0] = gb0;
    Bs4[cur][wi1] = gb1;
    if (ks < 7) {
      ga0 = Ab[(ks + 1) * 8];
      ga1 = Ab[(ks + 1) * 8 + 1];
      gb0 = Bb[(ks + 1) * 8];
      gb1 = Bb[(ks + 1) * 8 + 1];
    }
    __syncthreads();
    const char* Ac = (const char*)As4[cur];
    const char* Bc = (const char*)Bs4[cur];
#pragma unroll
    for (int kk = 0; kk < 2; ++kk) {
      const int off = (kk * 64 + hi16) ^ rsw;
      bf16x8 af0 = *(const bf16x8*)(Ac + rowA0 + off);
      bf16x8 af1 = *(const bf16x8*)(Ac + rowA1 + off);
      bf16x8 bf0 = *(const bf16x8*)(Bc + rowB0 + off);
      bf16x8 bf1 = *(const bf16x8*)(Bc + rowB1 + off);
      acc00 = __builtin_amdgcn_mfma_f32_16x16x32_bf16(af0, bf0, acc00, 0, 0, 0);
      acc01 = __builtin_amdgcn_mfma_f32_16x16x32_bf16(af0, bf1, acc01, 0, 0, 0);
      acc10 = __builtin_amdgcn_mfma_f32_16x16x32_bf16(af1, bf0, acc10, 0, 0, 0);
      acc11 = __builtin_amdgcn_mfma_f32_16x16x32_bf16(af1, bf1, acc11, 0, 0, 0);
    }
  }

  // fused epilogue: F(s) via LUT, weighted, atomic-accumulated
  const float pwp = pw[p];
  const int ar = a0 + qr + (lane >> 4) * 4;
  const int bc = b0 + qc + l15;
#pragma unroll
  for (int j = 0; j < 4; ++j) {
    float sv[4] = {acc00[j], acc01[j], acc10[j], acc11[j]};
    int id[4] = {(ar + j) * K + bc, (ar + j) * K + bc + 16,
                 (ar + 16 + j) * K + bc, (ar + 16 + j) * K + bc + 16};
#pragma unroll
    for (int q = 0; q < 4; ++q) {
      float s = sv[q];
      float u = fminf(fmaxf((s + 1.0f) * (LN / 2), 0.0f), (float)LN);
      int i = min((int)u, LN - 1);
      float fr = u - (float)i;
      float F = fmaf(fr, lt[i + 1] - lt[i], lt[i]);
      atomicAdd(&accS[id[q]], F * pwp);
      atomicAdd(&accN[id[q]], (s != 0.0f) ? pwp : 0.0f);
    }
  }
}

// ---- finalize: divide ----
__global__ __launch_bounds__(256) void kdiv(const float* __restrict__ accS,
                                            const float* __restrict__ accN,
                                            float* __restrict__ out) {
  int gi = blockIdx.x * 256 + threadIdx.x;
  out[gi] = accS[gi] / (accN[gi] + 1e-6f);
}

// ---- emergency fallback (no workspace needed) ----
__global__ __launch_bounds__(256) void kmono(const float* __restrict__ enroll,
                                             const float* __restrict__ test,
                                             const float* __restrict__ pho_w,
                                             const float* __restrict__ fc1w,
                                             const float* __restrict__ fc1b,
                                             const float* __restrict__ fc2w,
                                             float* __restrict__ out) {
  __shared__ float w1[C], b1[C], w2[C], pwm[P];
  const int t = threadIdx.x;
  if (t < C) {
    w1[t] = fc1w[t];
    b1[t] = fc1b[t];
    w2[t] = fc2w[t];
  }
  if (t < P) {
    float wmin = pho_w[0], wmax = pho_w[0];
    for (int i = 1; i < P; ++i) {
      float v = pho_w[i];
      wmin = fminf(wmin, v);
      wmax = fmaxf(wmax, v);
    }
    pwm[t] = (pho_w[t] - wmin) / (1e-6f + wmax - wmin);
  }
  __syncthreads();
  const int idx = blockIdx.x * 256 + t;
  const int a = idx >> 8, b = idx & 255;
  float score = 0.f, nz = 0.f;
  for (int p = 0; p < P; ++p) {
    float se = 0.f, st = 0.f, dot = 0.f;
    for (int d = 0; d < D; ++d) {
      float ev = enroll[((size_t)a * D + d) * P + p];
      float tv = test[((size_t)b * D + d) * P + p];
      se = fmaf(ev, ev, se);
      st = fmaf(tv, tv, st);
      dot = fmaf(ev, tv, dot);
    }
    float s = dot * (1.0f / fmaxf(sqrtf(se), 1e-12f)) * (1.0f / fmaxf(sqrtf(st), 1e-12f));
    float g = 0.f;
#pragma unroll
    for (int c = 0; c < C; ++c) g = fmaf(tanh_fast(fmaf(s, w1[c], b1[c])), w2[c], g);
    float f = tanh_fast(g * s);
    score = fmaf(f, pwm[p], score);
    if (s != 0.0f) nz += pwm[p];
  }
  out[idx] = score / (nz + 1e-6f);
}

}  // namespace

extern "C" void kernel_launch(void* const* d_in, const int* in_sizes, int n_in,
                              void* d_out, int out_size, void* d_ws, size_t ws_size,
                              hipStream_t stream) {
  const float* enroll = (const float*)d_in[0];
  const float* test = (const float*)d_in[1];
  const float* pho_w = (const float*)d_in[2];
  const float* fc1w = (const float*)d_in[3];
  const float* fc1b = (const float*)d_in[4];
  const float* fc2w = (const float*)d_in[5];
  float* out = (float*)d_out;

  const size_t sz_pair = (size_t)P * K * 256 * sizeof(unsigned);  // 10.49 MB each
  const size_t need = 2 * sz_pair + (size_t)2 * NOUT * sizeof(float) +
                      (size_t)(LN + 1) * sizeof(float) + (size_t)P * sizeof(float);
  if (ws_size >= need) {
    unsigned* Ep = (unsigned*)d_ws;
    unsigned* Tp = Ep + sz_pair / 4;
    float* acc = (float*)(Tp + sz_pair / 4);  // accS | accN
    float* tab = acc + 2 * NOUT;
    float* pw = tab + (LN + 1);

    const int init_elems = 2 * NOUT + (LN + 1) + P;
    kinit<<<(init_elems + 255) / 256, 256, 0, stream>>>(fc1w, fc1b, fc2w, pho_w, acc, tab, pw);
    kprep<<<2 * K, 256, 0, stream>>>(enroll, test, Ep, Tp);
    kgemm<<<dim3(K / 64, K / 64, P), 256, 0, stream>>>((const uint4*)Ep, (const uint4*)Tp,
                                                       tab, pw, acc, acc + NOUT);
    kdiv<<<NOUT / 256, 256, 0, stream>>>(acc, acc + NOUT, out);
  } else {
    kmono<<<(K * K) / 256, 256, 0, stream>>>(enroll, test, pho_w, fc1w, fc1b, fc2w, out);
  }
}

// Round 6
// 43.329 us; speedup vs baseline: 3.6428x; 1.1759x over previous
//
#include <hip/hip_runtime.h>
#include <math.h>

namespace {

constexpr int K = 256, D = 256, P = 40, C = 32;
constexpr int LN = 2048;     // LUT intervals over s in [-1,1]
constexpr int NOUT = K * K;  // 65536
constexpr int ZB = 128;                    // zero-blocks: 128*256*16B = 512 KB (accS+corr)
constexpr int LB = (LN + 1 + 255) / 256;   // LUT blocks

typedef __attribute__((ext_vector_type(8))) short bf16x8;
typedef __attribute__((ext_vector_type(4))) float f32x4;

__device__ __forceinline__ float tanh_fast(float x) {
  float e = __expf(2.0f * x);
  return 1.0f - __fdividef(2.0f, e + 1.0f);
}

// round-to-nearest bf16 split: (hi16) | (lo16 << 16); hi+lo ~ v to ~2^-18 rel
__device__ __forceinline__ unsigned bf16pair(float v) {
  unsigned u = __float_as_uint(v);
  unsigned hi = (u + 0x7fffu + ((u >> 16) & 1u)) >> 16;
  float lo = v - __uint_as_float(hi << 16);
  unsigned ul = __float_as_uint(lo);
  unsigned lo16 = (ul + 0x7fffu + ((ul >> 16) & 1u)) >> 16;
  return hi | (lo16 << 16);
}

__device__ __forceinline__ void gload16(const void* g, void* l) {
  __builtin_amdgcn_global_load_lds((const __attribute__((address_space(1))) void*)g,
                                   (__attribute__((address_space(3))) void*)l, 16, 0, 0);
}

// ---- prep (+ merged init): blocks [0,2K): L2-norm+transpose+bf16-split;
//      blocks [2K, 2K+ZB): zero accS/corr; then LUT blocks; then pw block ----
__global__ __launch_bounds__(256) void kprep(const float* __restrict__ e,
                                             const float* __restrict__ ts,
                                             const float* __restrict__ fc1w,
                                             const float* __restrict__ fc1b,
                                             const float* __restrict__ fc2w,
                                             const float* __restrict__ pho_w,
                                             unsigned* __restrict__ Ep,
                                             unsigned* __restrict__ Tp,
                                             float* __restrict__ accz,
                                             float* __restrict__ tab,
                                             float* __restrict__ pwv) {
  const int bid = blockIdx.x;
  const int t = threadIdx.x;
  if (bid >= 2 * K) {
    int ib = bid - 2 * K;
    if (ib < ZB) {
      ((float4*)accz)[(size_t)ib * 256 + t] = make_float4(0.f, 0.f, 0.f, 0.f);
      return;
    }
    ib -= ZB;
    if (ib < LB) {
      int i = ib * 256 + t;
      if (i <= LN) {
        float s = -1.0f + (float)i * (2.0f / LN);
        float g = 0.f;
#pragma unroll
        for (int c = 0; c < C; ++c) g = fmaf(tanh_fast(fmaf(s, fc1w[c], fc1b[c])), fc2w[c], g);
        tab[i] = tanh_fast(g * s);
      }
      return;
    }
    // pw block: pwv[0..P) normalized weights, pwv[P] = their sum
    float wmin = pho_w[0], wmax = pho_w[0];
    for (int i = 1; i < P; ++i) {
      float v = pho_w[i];
      wmin = fminf(wmin, v);
      wmax = fmaxf(wmax, v);
    }
    float inv = 1.0f / (1e-6f + wmax - wmin);
    if (t < P) pwv[t] = (pho_w[t] - wmin) * inv;
    if (t == 64) {
      float sum = 0.f;
      for (int i = 0; i < P; ++i) sum += (pho_w[i] - wmin) * inv;
      pwv[P] = sum;
    }
    return;
  }
  // ---- prep path ----
  __shared__ float tile[D * 41];  // padded stride 41: conflict-free columns
  __shared__ float red[240];
  __shared__ float inv[P];
  const float* x = (bid < K) ? e : ts;
  unsigned* xt = (bid < K) ? Ep : Tp;
  const int a = bid & (K - 1);
  const float4* src4 = (const float4*)(x + (size_t)a * D * P);
#pragma unroll
  for (int i4 = t; i4 < (D * P) / 4; i4 += 256) {
    float4 v = src4[i4];  // row = 10 float4 -> each float4 within one d
    int d = i4 / 10;
    int p0 = (i4 - d * 10) * 4;
    float* dst = &tile[d * 41 + p0];
    dst[0] = v.x;
    dst[1] = v.y;
    dst[2] = v.z;
    dst[3] = v.w;
  }
  __syncthreads();
  if (t < 240) {  // 6 threads per column
    int p = t / 6, j = t - (t / 6) * 6;
    float ss = 0.f;
    for (int d = j; d < D; d += 6) {
      float v = tile[d * 41 + p];
      ss = fmaf(v, v, ss);
    }
    red[t] = ss;
  }
  __syncthreads();
  if (t < P) {
    float ss = red[t * 6] + red[t * 6 + 1] + red[t * 6 + 2] + red[t * 6 + 3] +
               red[t * 6 + 4] + red[t * 6 + 5];
    inv[t] = 1.0f / fmaxf(sqrtf(ss), 1e-12f);
  }
  __syncthreads();
  for (int i = t; i < D * P; i += 256) {
    int p = i >> 8, d = i & 255;
    xt[((size_t)p * K + a) * 256 + d] = bf16pair(tile[d * 41 + p] * inv[p]);
  }
}

// ---- per-p MFMA GEMM (split-K=512 bf16), 64x32 tile, gload_lds staging,
//      fused LUT epilogue + score atomics (nz via rare zero-correction) ----
__global__ __launch_bounds__(256) void kgemm(const unsigned* __restrict__ Ep,
                                             const unsigned* __restrict__ Tp,
                                             const float* __restrict__ tab,
                                             const float* __restrict__ pwv,
                                             float* __restrict__ accS,
                                             float* __restrict__ corr) {
  __shared__ uint4 As4[2][512];  // 2 x 8 KiB: 64 rows x 128 B, swizzled content
  __shared__ uint4 Bs4[2][256];  // 2 x 4 KiB: 32 rows x 128 B
  __shared__ __align__(16) float lt[LN + 4];  // 8.2 KiB
  const int p = blockIdx.z;
  const int b0 = blockIdx.x * 32;
  const int a0 = blockIdx.y * 64;
  const int t = threadIdx.x, lane = t & 63, w = t >> 6;

  {  // stage LUT (visibility via the K-loop barriers)
    const float4* t4 = (const float4*)tab;
    float4* l4 = (float4*)lt;
#pragma unroll
    for (int i = t; i < LN / 4; i += 256) l4[i] = t4[i];
    if (t == 0) lt[LN] = tab[LN];
  }

  // staging geometry: each wave fills A rows [w*16, w*16+16) and B rows [w*8, w*8+8)
  const int lr = lane >> 3, sb = lane & 7;
  const int rA0 = w * 16 + lr, rA1 = w * 16 + 8 + lr, rB = w * 8 + lr;
  const char* srcA0 = (const char*)Ep + ((size_t)p * K + a0 + rA0) * 1024 +
                      ((sb * 16) ^ ((rA0 & 7) << 4));
  const char* srcA1 = (const char*)Ep + ((size_t)p * K + a0 + rA1) * 1024 +
                      ((sb * 16) ^ ((rA1 & 7) << 4));
  const char* srcB = (const char*)Tp + ((size_t)p * K + b0 + rB) * 1024 +
                     ((sb * 16) ^ ((rB & 7) << 4));
  char* dA0 = (char*)&As4[0][0] + w * 2048;
  char* dA1 = (char*)&As4[1][0] + w * 2048;
  char* dB0 = (char*)&Bs4[0][0] + w * 1024;
  char* dB1 = (char*)&Bs4[1][0] + w * 1024;

  // fragment read geometry (swizzled reads match swizzled staging content)
  const int qr = (w >> 1) * 32, qc = (w & 1) * 16;
  const int l15 = lane & 15, hi16 = (lane >> 4) * 16;
  const int rsw = (l15 & 7) << 4;
  const int rowA0 = (qr + l15) * 128, rowA1 = (qr + 16 + l15) * 128;
  const int rowB0 = (qc + l15) * 128;

  // prologue: fill buffer 0
  gload16(srcA0, dA0);
  gload16(srcA1, dA0 + 1024);
  gload16(srcB, dB0);

  f32x4 acc0 = {0.f, 0.f, 0.f, 0.f}, acc1 = {0.f, 0.f, 0.f, 0.f};
  for (int ks = 0; ks < 8; ++ks) {
    const int cur = ks & 1;
    __syncthreads();  // drains in-flight gloads -> buf[cur] ready
    if (ks < 7) {     // prefetch next K-step into other buffer (flies under compute)
      char* dan = cur ? dA0 : dA1;
      char* dbn = cur ? dB0 : dB1;
      gload16(srcA0 + (ks + 1) * 128, dan);
      gload16(srcA1 + (ks + 1) * 128, dan + 1024);
      gload16(srcB + (ks + 1) * 128, dbn);
    }
    const char* Ac = cur ? (const char*)As4[1] : (const char*)As4[0];
    const char* Bc = cur ? (const char*)Bs4[1] : (const char*)Bs4[0];
#pragma unroll
    for (int kk = 0; kk < 2; ++kk) {
      const int off = (kk * 64 + hi16) ^ rsw;
      bf16x8 af0 = *(const bf16x8*)(Ac + rowA0 + off);
      bf16x8 af1 = *(const bf16x8*)(Ac + rowA1 + off);
      bf16x8 bf0 = *(const bf16x8*)(Bc + rowB0 + off);
      acc0 = __builtin_amdgcn_mfma_f32_16x16x32_bf16(af0, bf0, acc0, 0, 0, 0);
      acc1 = __builtin_amdgcn_mfma_f32_16x16x32_bf16(af1, bf0, acc1, 0, 0, 0);
    }
  }

  // fused epilogue: F(s) via LUT; score atomics; nz handled as (sum - rare correction)
  const float pwp = pwv[p];
  const int ar = a0 + qr + (lane >> 4) * 4;
  const int bc = b0 + qc + l15;
#pragma unroll
  for (int j = 0; j < 4; ++j) {
    float sv[2] = {acc0[j], acc1[j]};
    int id[2] = {(ar + j) * K + bc, (ar + 16 + j) * K + bc};
#pragma unroll
    for (int q = 0; q < 2; ++q) {
      float s = sv[q];
      float u = fminf(fmaxf((s + 1.0f) * (LN / 2), 0.0f), (float)LN);
      int i = min((int)u, LN - 1);
      float fr = u - (float)i;
      float F = fmaf(fr, lt[i + 1] - lt[i], lt[i]);
      atomicAdd(&accS[id[q]], F * pwp);
      if (s == 0.0f) atomicAdd(&corr[id[q]], pwp);  // never taken on real data
    }
  }
}

// ---- finalize ----
__global__ __launch_bounds__(256) void kdiv(const float* __restrict__ accS,
                                            const float* __restrict__ corr,
                                            const float* __restrict__ pwv,
                                            float* __restrict__ out) {
  int gi = blockIdx.x * 256 + threadIdx.x;
  out[gi] = accS[gi] / (pwv[P] - corr[gi] + 1e-6f);
}

// ---- emergency fallback (no workspace needed) ----
__global__ __launch_bounds__(256) void kmono(const float* __restrict__ enroll,
                                             const float* __restrict__ test,
                                             const float* __restrict__ pho_w,
                                             const float* __restrict__ fc1w,
                                             const float* __restrict__ fc1b,
                                             const float* __restrict__ fc2w,
                                             float* __restrict__ out) {
  __shared__ float w1[C], b1[C], w2[C], pwm[P];
  const int t = threadIdx.x;
  if (t < C) {
    w1[t] = fc1w[t];
    b1[t] = fc1b[t];
    w2[t] = fc2w[t];
  }
  if (t < P) {
    float wmin = pho_w[0], wmax = pho_w[0];
    for (int i = 1; i < P; ++i) {
      float v = pho_w[i];
      wmin = fminf(wmin, v);
      wmax = fmaxf(wmax, v);
    }
    pwm[t] = (pho_w[t] - wmin) / (1e-6f + wmax - wmin);
  }
  __syncthreads();
  const int idx = blockIdx.x * 256 + t;
  const int a = idx >> 8, b = idx & 255;
  float score = 0.f, nz = 0.f;
  for (int p = 0; p < P; ++p) {
    float se = 0.f, st = 0.f, dot = 0.f;
    for (int d = 0; d < D; ++d) {
      float ev = enroll[((size_t)a * D + d) * P + p];
      float tv = test[((size_t)b * D + d) * P + p];
      se = fmaf(ev, ev, se);
      st = fmaf(tv, tv, st);
      dot = fmaf(ev, tv, dot);
    }
    float s = dot * (1.0f / fmaxf(sqrtf(se), 1e-12f)) * (1.0f / fmaxf(sqrtf(st), 1e-12f));
    float g = 0.f;
#pragma unroll
    for (int c = 0; c < C; ++c) g = fmaf(tanh_fast(fmaf(s, w1[c], b1[c])), w2[c], g);
    float f = tanh_fast(g * s);
    score = fmaf(f, pwm[p], score);
    if (s != 0.0f) nz += pwm[p];
  }
  out[idx] = score / (nz + 1e-6f);
}

}  // namespace

extern "C" void kernel_launch(void* const* d_in, const int* in_sizes, int n_in,
                              void* d_out, int out_size, void* d_ws, size_t ws_size,
                              hipStream_t stream) {
  const float* enroll = (const float*)d_in[0];
  const float* test = (const float*)d_in[1];
  const float* pho_w = (const float*)d_in[2];
  const float* fc1w = (const float*)d_in[3];
  const float* fc1b = (const float*)d_in[4];
  const float* fc2w = (const float*)d_in[5];
  float* out = (float*)d_out;

  const size_t sz_pair = (size_t)P * K * 256 * sizeof(unsigned);  // 10.49 MB each
  const size_t need = 2 * sz_pair + (size_t)2 * NOUT * sizeof(float) +
                      (size_t)(LN + 8) * sizeof(float) + (size_t)(P + 1) * sizeof(float);
  if (ws_size >= need) {
    unsigned* Ep = (unsigned*)d_ws;
    unsigned* Tp = Ep + sz_pair / 4;
    float* accS = (float*)(Tp + sz_pair / 4);
    float* corr = accS + NOUT;
    float* tab = corr + NOUT;
    float* pwv = tab + (LN + 4);

    kprep<<<2 * K + ZB + LB + 1, 256, 0, stream>>>(enroll, test, fc1w, fc1b, fc2w, pho_w,
                                                   Ep, Tp, accS, tab, pwv);
    kgemm<<<dim3(K / 32, K / 64, P), 256, 0, stream>>>(Ep, Tp, tab, pwv, accS, corr);
    kdiv<<<NOUT / 256, 256, 0, stream>>>(accS, corr, pwv, out);
  } else {
    kmono<<<(K * K) / 256, 256, 0, stream>>>(enroll, test, pho_w, fc1w, fc1b, fc2w, out);
  }
}